// Round 7
// baseline (117.887 us; speedup 1.0000x reference)
//
#include <hip/hip_runtime.h>
#include <hip/hip_bf16.h>
#include <cfloat>
#include <math.h>

#define BB 4
#define NR 180
#define CC 512
#define HH 48
#define WW 48
#define FF (CC*4)      // 2048
#define OO 64
#define EPSV 1e-5f
#define NCH 4

// ---- ws layout ----
// featB : BB*HW*CC ushort (MAPPED u16 domain)
// W1T4  : [512][64][4] float   (W1T4[k>>2][o][k&3] = W1[o][k])
// pp    : [b*NR+n][ch][f] ushort (MAPPED domain, ReLU'd)
//
// XCD affinity: workgroup->XCD round-robins linear block id (%8 heuristic).
// We map batch b to XCD pair {2b,2b+1} in BOTH the featB writer (k_prep) and
// reader (k_pool): featB[b] = 2.36 MB < 4 MiB per-XCD L2 -> pool reads hit L2
// instead of L3. Perf heuristic only; correctness independent of mapping.

typedef unsigned short us2 __attribute__((ext_vector_type(2)));

__device__ __forceinline__ unsigned pmax(unsigned a, unsigned b) {
    return __builtin_bit_cast(unsigned, __builtin_elementwise_max(
        __builtin_bit_cast(us2, a), __builtin_bit_cast(us2, b)));
}
__device__ __forceinline__ uint4 pmax4(uint4 a, uint4 b) {
    return make_uint4(pmax(a.x,b.x), pmax(a.y,b.y), pmax(a.z,b.z), pmax(a.w,b.w));
}
__device__ __forceinline__ unsigned mapb(float f) {      // float -> mapped u16
    unsigned fu = __float_as_uint(f);
    unsigned u = fu >> 16;
    return (fu >> 31) ? (~u & 0xFFFFu) : (u | 0x8000u);
}
__device__ __forceinline__ void unmap2(unsigned m, float& lo, float& hi) {
    unsigned t = ((~m) >> 15) & 0x00010001u;
    unsigned u = m ^ (0x80008000u ^ (t * 0x7FFFu));
    lo = __uint_as_float(u << 16);
    hi = __uint_as_float(u & 0xffff0000u);
}

// ---------------- Kernel 1: transposes, XCD-affine --------------------------
// L < 4608 : feature transpose. xcd=L%8, b=xcd>>1, p=xcd&1, t=L>>3 (0..575),
//            tile m = 2t+p (0..1151): s-tile = m%72, c-tile = m/72.
// L >= 4608: W1 -> W1T4, idx = L-4608 (0..127).
__global__ __launch_bounds__(256) void k_prep(const float* __restrict__ feat,
                                              const float* __restrict__ W1,
                                              ushort* __restrict__ featB,
                                              float* __restrict__ W1T4) {
    __shared__ float tile[32][33];
    int t = threadIdx.x;
    int L = blockIdx.x;

    if (L < 4608) {
        const int S = HH * WW;                 // 2304
        int xcd = L & 7;
        int b   = xcd >> 1;
        int m   = ((L >> 3) << 1) | (xcd & 1); // 0..1151
        int s0  = (m % 72) * 32;
        int c0  = (m / 72) * 32;
        const float* src = feat + (size_t)b * CC * S;
        ushort* dst = featB + (size_t)b * S * CC;

        int cl = t >> 3;
        int sx = (t & 7) << 2;
        float4 v = *(const float4*)(src + (size_t)(c0 + cl) * S + s0 + sx);
        tile[cl][sx] = v.x; tile[cl][sx+1] = v.y; tile[cl][sx+2] = v.z; tile[cl][sx+3] = v.w;
        __syncthreads();

        int sl = t >> 3;
        int c4 = (t & 7) << 2;
        unsigned u0 = mapb(tile[c4][sl])   | (mapb(tile[c4+1][sl]) << 16);
        unsigned u1 = mapb(tile[c4+2][sl]) | (mapb(tile[c4+3][sl]) << 16);
        *(uint2*)(dst + (size_t)(s0 + sl) * CC + c0 + c4) = make_uint2(u0, u1);
    } else {
        int kt = L - 4608;                         // 0..127
        int k0 = (kt >> 1) * 32, o0 = (kt & 1) * 32;
        int tx = t & 31, ty = t >> 5;
        #pragma unroll
        for (int k = 0; k < 4; k++) {
            int row = ty + k * 8;
            tile[row][tx] = W1[(size_t)(o0 + row) * FF + (k0 + tx)];
        }
        __syncthreads();
        #pragma unroll
        for (int k = 0; k < 4; k++) {
            int row = ty + k * 8;
            int kk = k0 + row;
            int o  = o0 + tx;
            W1T4[(size_t)(kk >> 2) * 256 + o * 4 + (kk & 3)] = tile[tx][row];
        }
    }
}

// ---------------- Kernel 2: ROI pool, mapped-int, XCD-affine ----------------
// 2880 linear blocks: xcd=L%8, b=xcd>>1, p=xcd&1, t=L>>3 (0..359),
// ch = 2p + (t&1), n = t>>1.
__global__ __launch_bounds__(256, 6) void k_pool(const ushort* __restrict__ featB,
                                                 const float* __restrict__ rois,
                                                 ushort* __restrict__ pp) {
    __shared__ unsigned lu[4][16][64];        // 16 KB, conflict-free
    int L = blockIdx.x;
    int xcd = L & 7;
    int b   = xcd >> 1;
    int tt  = L >> 3;                         // 0..359
    int ch  = ((xcd & 1) << 1) | (tt & 1);    // 0..3
    int n   = tt >> 1;                        // 0..179
    int tid = threadIdx.x;
    int g = tid >> 6, c = tid & 63;

    const float* roi = rois + ((size_t)b * NR + n) * 4;
    int r0 = (int)(roi[0] * 0.25f);
    int r1 = (int)(roi[1] * 0.25f);
    int r2 = (int)ceilf(roi[2] * 0.25f);
    int r3 = (int)ceilf(roi[3] * 0.25f);
    int hs  = r2 - r0 + 1;
    int wsz = r3 - r1 + 1;
    int eh0 = (hs + 1) >> 1, sh1 = hs >> 1;
    int ew0 = (wsz + 1) >> 1, sw1 = wsz >> 1;

    const uint4 Z = make_uint4(0,0,0,0);
    uint4 q00 = Z, q01 = Z, q10 = Z, q11 = Z;

    for (int Lr = ch * 4 + g; Lr < hs; Lr += 16) {
        const uint4* rp = (const uint4*)(featB + ((size_t)((b * HH + r0 + Lr) * WW + r1)) * CC) + c;
        uint4 cm0 = Z, cm1 = Z;
        {
            int e = ew0 - 1;
            for (int w = 0; w < ew0; w += 8) {
                uint4 u0 = rp[(size_t)64 * w];
                uint4 u1 = rp[(size_t)64 * min(w + 1, e)];
                uint4 u2 = rp[(size_t)64 * min(w + 2, e)];
                uint4 u3 = rp[(size_t)64 * min(w + 3, e)];
                uint4 u4 = rp[(size_t)64 * min(w + 4, e)];
                uint4 u5 = rp[(size_t)64 * min(w + 5, e)];
                uint4 u6 = rp[(size_t)64 * min(w + 6, e)];
                uint4 u7 = rp[(size_t)64 * min(w + 7, e)];
                cm0 = pmax4(cm0, pmax4(pmax4(pmax4(u0,u1), pmax4(u2,u3)),
                                       pmax4(pmax4(u4,u5), pmax4(u6,u7))));
            }
        }
        {
            int e = wsz - 1;
            for (int w = sw1; w < wsz; w += 8) {
                uint4 u0 = rp[(size_t)64 * w];
                uint4 u1 = rp[(size_t)64 * min(w + 1, e)];
                uint4 u2 = rp[(size_t)64 * min(w + 2, e)];
                uint4 u3 = rp[(size_t)64 * min(w + 3, e)];
                uint4 u4 = rp[(size_t)64 * min(w + 4, e)];
                uint4 u5 = rp[(size_t)64 * min(w + 5, e)];
                uint4 u6 = rp[(size_t)64 * min(w + 6, e)];
                uint4 u7 = rp[(size_t)64 * min(w + 7, e)];
                cm1 = pmax4(cm1, pmax4(pmax4(pmax4(u0,u1), pmax4(u2,u3)),
                                       pmax4(pmax4(u4,u5), pmax4(u6,u7))));
            }
        }
        if (Lr <  eh0) { q00 = pmax4(q00, cm0); q01 = pmax4(q01, cm1); }
        if (Lr >= sh1) { q10 = pmax4(q10, cm0); q11 = pmax4(q11, cm1); }
    }

    // repack: lu[g][m*4+{0..3}][c] = {(ch2m,oi0),(ch2m,oi1),(ch2m+1,oi0),(ch2m+1,oi1)}
    {
        unsigned a, b2;
        a = q00.x; b2 = q01.x;
        lu[g][0*4 + 0][c] = (a & 0xFFFFu) | (b2 << 16);
        lu[g][0*4 + 2][c] = (a >> 16)     | (b2 & 0xFFFF0000u);
        a = q10.x; b2 = q11.x;
        lu[g][0*4 + 1][c] = (a & 0xFFFFu) | (b2 << 16);
        lu[g][0*4 + 3][c] = (a >> 16)     | (b2 & 0xFFFF0000u);
        a = q00.y; b2 = q01.y;
        lu[g][1*4 + 0][c] = (a & 0xFFFFu) | (b2 << 16);
        lu[g][1*4 + 2][c] = (a >> 16)     | (b2 & 0xFFFF0000u);
        a = q10.y; b2 = q11.y;
        lu[g][1*4 + 1][c] = (a & 0xFFFFu) | (b2 << 16);
        lu[g][1*4 + 3][c] = (a >> 16)     | (b2 & 0xFFFF0000u);
        a = q00.z; b2 = q01.z;
        lu[g][2*4 + 0][c] = (a & 0xFFFFu) | (b2 << 16);
        lu[g][2*4 + 2][c] = (a >> 16)     | (b2 & 0xFFFF0000u);
        a = q10.z; b2 = q11.z;
        lu[g][2*4 + 1][c] = (a & 0xFFFFu) | (b2 << 16);
        lu[g][2*4 + 3][c] = (a >> 16)     | (b2 & 0xFFFF0000u);
        a = q00.w; b2 = q01.w;
        lu[g][3*4 + 0][c] = (a & 0xFFFFu) | (b2 << 16);
        lu[g][3*4 + 2][c] = (a >> 16)     | (b2 & 0xFFFF0000u);
        a = q10.w; b2 = q11.w;
        lu[g][3*4 + 1][c] = (a & 0xFFFFu) | (b2 << 16);
        lu[g][3*4 + 3][c] = (a >> 16)     | (b2 & 0xFFFF0000u);
    }
    __syncthreads();

    int c2 = tid & 63, j0 = (tid >> 6) * 4;
    unsigned ou[4];
    #pragma unroll
    for (int jj = 0; jj < 4; jj++) {
        int j = j0 + jj;
        unsigned m = pmax(pmax(lu[0][j][c2], lu[1][j][c2]),
                          pmax(lu[2][j][c2], lu[3][j][c2]));
        ou[jj] = pmax(m, 0x80008000u);        // ReLU: mapped(+0)=0x8000
    }
    unsigned* dst = (unsigned*)(pp + ((size_t)(b * NR + n) * NCH + ch) * FF);
    *(uint4*)(dst + c2 * 16 + j0) = make_uint4(ou[0], ou[1], ou[2], ou[3]);
}

// ---------------- Kernel 3: reduce chunks + unmap + BN1 + GEMM + BN2 --------
__global__ __launch_bounds__(1024) void k_gemm(const ushort* __restrict__ pp,
                                               const float* __restrict__ W1T4,
                                               const float* __restrict__ bl1,
                                               const float* __restrict__ g1,
                                               const float* __restrict__ b1,
                                               const float* __restrict__ g2,
                                               const float* __restrict__ b2,
                                               float* __restrict__ out) {
    __shared__ float xs[BB][FF];          // 32 KB
    __shared__ float pd[16][BB][OO];      // 16 KB
    __shared__ float pw[16][OO];          // 4 KB
    __shared__ float part_s[16], part_q[16];
    __shared__ float sm2[4], sq2[4];
    int n = blockIdx.x;
    int tid = threadIdx.x;

    float s_acc = 0.f, q_acc = 0.f;
    #pragma unroll
    for (int k2 = 0; k2 < 2; k2++) {
        int gi = tid + (k2 << 10);
        int bb = gi >> 9;
        int idx = gi & 511;
        const unsigned* base = (const unsigned*)(pp + ((size_t)(bb * NR + n)) * NCH * FF);
        uint2 m = *(const uint2*)(base + 0 * (FF / 2) + idx * 2);
        #pragma unroll
        for (int cch = 1; cch < NCH; cch++) {
            uint2 u = *(const uint2*)(base + cch * (FF / 2) + idx * 2);
            m.x = pmax(m.x, u.x);
            m.y = pmax(m.y, u.y);
        }
        float v0, v1, v2, v3;
        unmap2(m.x, v0, v1);
        unmap2(m.y, v2, v3);
        *(float4*)&xs[bb][idx << 2] = make_float4(v0, v1, v2, v3);
        s_acc += v0 + v1 + v2 + v3;
        q_acc += v0*v0 + v1*v1 + v2*v2 + v3*v3;
    }
    for (int off = 32; off; off >>= 1) {
        s_acc += __shfl_down(s_acc, off);
        q_acc += __shfl_down(q_acc, off);
    }
    if ((tid & 63) == 0) { part_s[tid >> 6] = s_acc; part_q[tid >> 6] = q_acc; }
    __syncthreads();
    float ts = 0.f, tq = 0.f;
    #pragma unroll
    for (int i = 0; i < 16; i++) { ts += part_s[i]; tq += part_q[i]; }
    const float inv1 = 1.f / (float)(BB * FF);
    float mean = ts * inv1;
    float var  = tq * inv1 - mean * mean;
    float a1n  = g1[n] * rsqrtf(var + EPSV);
    float c1n  = b1[n] - mean * a1n;

    int sc = tid >> 6;
    int o  = tid & 63;
    int k4a = sc << 5;
    float a0 = 0.f, a1 = 0.f, a2 = 0.f, a3 = 0.f, wsum = 0.f;
    #pragma unroll 4
    for (int k4 = k4a; k4 < k4a + 32; k4++) {
        float4 w4 = *(const float4*)(W1T4 + (size_t)k4 * 256 + o * 4);
        float4 x0 = *(const float4*)&xs[0][k4 << 2];
        float4 x1 = *(const float4*)&xs[1][k4 << 2];
        float4 x2 = *(const float4*)&xs[2][k4 << 2];
        float4 x3 = *(const float4*)&xs[3][k4 << 2];
        wsum += w4.x + w4.y + w4.z + w4.w;
        a0 += w4.x*x0.x + w4.y*x0.y + w4.z*x0.z + w4.w*x0.w;
        a1 += w4.x*x1.x + w4.y*x1.y + w4.z*x1.z + w4.w*x1.w;
        a2 += w4.x*x2.x + w4.y*x2.y + w4.z*x2.z + w4.w*x2.w;
        a3 += w4.x*x3.x + w4.y*x3.y + w4.z*x3.z + w4.w*x3.w;
    }
    pd[sc][0][o] = a0; pd[sc][1][o] = a1; pd[sc][2][o] = a2; pd[sc][3][o] = a3;
    pw[sc][o] = wsum;
    __syncthreads();

    float y = 0.f;
    int b = tid >> 6;
    if (tid < 256) {
        float dot = 0.f, wsm = 0.f;
        #pragma unroll
        for (int ss = 0; ss < 16; ss++) { dot += pd[ss][b][o]; wsm += pw[ss][o]; }
        y = a1n * dot + c1n * wsm + bl1[o];
        float rs = y, rq = y * y;
        for (int off = 32; off; off >>= 1) {
            rs += __shfl_down(rs, off);
            rq += __shfl_down(rq, off);
        }
        if (o == 0) { sm2[b] = rs; sq2[b] = rq; }
    }
    __syncthreads();
    if (tid < 256) {
        float sm  = sm2[0] + sm2[1] + sm2[2] + sm2[3];
        float sqm = sq2[0] + sq2[1] + sq2[2] + sq2[3];
        const float inv2 = 1.f / 256.f;
        float mean2 = sm * inv2;
        float var2  = sqm * inv2 - mean2 * mean2;
        float r2s = rsqrtf(var2 + EPSV);
        out[((size_t)b * NR + n) * OO + o] = (y - mean2) * r2s * g2[n] + b2[n];
    }
}

extern "C" void kernel_launch(void* const* d_in, const int* in_sizes, int n_in,
                              void* d_out, int out_size, void* d_ws, size_t ws_size,
                              hipStream_t stream) {
    const float* feat = (const float*)d_in[0];
    const float* rois = (const float*)d_in[1];
    const float* g1   = (const float*)d_in[2];
    const float* b1   = (const float*)d_in[3];
    const float* W1   = (const float*)d_in[4];
    const float* bl1  = (const float*)d_in[5];
    const float* g2   = (const float*)d_in[6];
    const float* b2   = (const float*)d_in[7];
    float* out = (float*)d_out;

    ushort* featB = (ushort*)d_ws;                    // mapped u16
    float*  W1T4  = (float*)(featB + (size_t)BB*HH*WW*CC);
    ushort* pp    = (ushort*)(W1T4 + (size_t)OO*FF);  // mapped u16

    k_prep<<<4736, 256, 0, stream>>>(feat, W1, featB, W1T4);
    k_pool<<<2880, 256, 0, stream>>>(featB, rois, pp);
    k_gemm<<<NR, 1024, 0, stream>>>(pp, W1T4, bl1, g1, b1, g2, b2, out);
}